// Round 10
// baseline (436.759 us; speedup 1.0000x reference)
//
#include <hip/hip_runtime.h>
#include <hip/hip_cooperative_groups.h>

namespace cg = cooperative_groups;

#define NIMG 8
#define IMH 2048
#define IMW 2048
#define GH 8
#define GW 8
#define NBINS 256
#define NTPI 64                        // tiles per image
#define CLIP_MAXF 256.0f               // clip_limit*pixels//NBINS = 65536//256
#define LUT_SCALE 0.0038909912109375f  // 255/65536, exact in f32
#define LOG_GAIN_F 2.5f

#define MM_BLOCKS 2048                 // k_minmax_in grid (64 KB per block)

typedef float f32x4 __attribute__((ext_vector_type(4)));

// fast bin: wave-uniform inv_den hoists the divide; __log2f = 1 v_log_f32
__device__ __forceinline__ int pix_bin(float v, float mn, float inv_den) {
    float xn = (v - mn) * inv_den;
    float t  = LOG_GAIN_F * __log2f(1.0f + xn);
    float xc = fminf(fmaxf(t, 0.0f), 1.0f);
    int b = (int)(xc * 256.0f);
    return min(max(b, 0), 255);
}

__device__ __forceinline__ void mm4(float4 v, float& mn, float& mx) {
    mn = fminf(mn, fminf(fminf(v.x, v.y), fminf(v.z, v.w)));
    mx = fmaxf(mx, fmaxf(fmaxf(v.x, v.y), fmaxf(v.z, v.w)));
}

template <int NWAVES>
__device__ __forceinline__ void block_minmax_all(float& mn, float& mx, int t) {
#pragma unroll
    for (int m = 32; m >= 1; m >>= 1) {
        mn = fminf(mn, __shfl_xor(mn, m, 64));
        mx = fmaxf(mx, __shfl_xor(mx, m, 64));
    }
    __shared__ float smn[NWAVES], smx[NWAVES];
    int wid = t >> 6, lid = t & 63;
    if (lid == 0) { smn[wid] = mn; smx[wid] = mx; }
    __syncthreads();
    mn = smn[0]; mx = smx[0];
#pragma unroll
    for (int i = 1; i < NWAVES; i++) { mn = fminf(mn, smn[i]); mx = fmaxf(mx, smx[i]); }
}

template <int NWAVES>
__device__ __forceinline__ void block_min_all(float& mn, int t) {
#pragma unroll
    for (int m = 32; m >= 1; m >>= 1) mn = fminf(mn, __shfl_xor(mn, m, 64));
    __shared__ float smn[NWAVES];
    int wid = t >> 6, lid = t & 63;
    if (lid == 0) smn[wid] = mn;
    __syncthreads();
    mn = smn[0];
#pragma unroll
    for (int i = 1; i < NWAVES; i++) mn = fminf(mn, smn[i]);
}

// ---- K1: per-block min/max of input; 8 loads in flight, 8 blocks/CU ----
__global__ __launch_bounds__(256, 8) void k_minmax_in(const float4* __restrict__ x,
                                                      float2* __restrict__ red) {
    int t = threadIdx.x;
    size_t base = (size_t)blockIdx.x * 4096 + t;   // 4096 float4 per block
    float mn = 3.4e38f, mx = -3.4e38f;
#pragma unroll
    for (int half = 0; half < 2; ++half) {
        float4 v[8];
#pragma unroll
        for (int k = 0; k < 8; ++k)
            v[k] = x[base + (size_t)(half * 8 + k) * 256];
#pragma unroll
        for (int k = 0; k < 8; ++k) mm4(v[k], mn, mx);
    }
    block_minmax_all<4>(mn, mx, t);
    if (t == 0) red[blockIdx.x] = make_float2(mn, mx);
}

// ---- K2: min/max reduce + bin + per-tile hist + clip/scan -> LUT (round-8) ----
// bins written QUADRANT-MAJOR: quadrant gq = img*256 + qy*16 + qx is a dense
// 128x128 byte block (uchar4 offset = (r&127)*32 + (c4&31)).
__global__ __launch_bounds__(512, 4) void k_hist(const float* __restrict__ x,
                                                 const float2* __restrict__ red1,
                                                 float* __restrict__ lut,
                                                 uchar4* __restrict__ binsq) {
    int t = threadIdx.x;

    float mn, mx;
    {
        float2 p0 = red1[t];
        float2 p1 = red1[t + 512];
        float2 p2 = red1[t + 1024];
        float2 p3 = red1[t + 1536];
        mn = fminf(fminf(p0.x, p1.x), fminf(p2.x, p3.x));
        mx = fmaxf(fmaxf(p0.y, p1.y), fmaxf(p2.y, p3.y));
        block_minmax_all<8>(mn, mx, t);
    }
    float inv_den = 1.0f / (mx - mn);

    __shared__ unsigned sh[NBINS];
    if (t < NBINS) sh[t] = 0u;
    __syncthreads();

    int tile = blockIdx.x;  // 0..63
    int img  = blockIdx.y;  // 0..7
    int ty = tile >> 3, tx = tile & 7;

    size_t base = ((size_t)img * IMH + (size_t)ty * 256) * IMW + (size_t)tx * 256;
    const float* xt = x + base;
    int lid = t & 63;
    int rowoff = t >> 6;   // 0..7
    int c4 = t & 63;       // 0..63 float4 columns
    int qc = c4 >> 5;
    int gq_base = img * 256 + (2 * ty) * 16 + (2 * tx) + qc;  // + 16*qr
    int qoff_c = c4 & 31;

    int hotcnt = 0;
    for (int it = 0; it < 16; ++it) {
        int r0 = (it << 4) + rowoff;
        int r1 = (it << 4) + 8 + rowoff;
        float4 va = *(const float4*)(xt + (size_t)r0 * IMW + (c4 << 2));
        float4 vb = *(const float4*)(xt + (size_t)r1 * IMW + (c4 << 2));

        int ba[4], bb[4];
        ba[0] = pix_bin(va.x, mn, inv_den); ba[1] = pix_bin(va.y, mn, inv_den);
        ba[2] = pix_bin(va.z, mn, inv_den); ba[3] = pix_bin(va.w, mn, inv_den);
        bb[0] = pix_bin(vb.x, mn, inv_den); bb[1] = pix_bin(vb.y, mn, inv_den);
        bb[2] = pix_bin(vb.z, mn, inv_den); bb[3] = pix_bin(vb.w, mn, inv_den);

#pragma unroll
        for (int j = 0; j < 4; j++) {
            hotcnt += (ba[j] == 255);
            if (ba[j] != 255) atomicAdd(&sh[ba[j]], 1u);
            hotcnt += (bb[j] == 255);
            if (bb[j] != 255) atomicAdd(&sh[bb[j]], 1u);
        }
        uchar4 qa, qb;
        qa.x = (unsigned char)ba[0]; qa.y = (unsigned char)ba[1];
        qa.z = (unsigned char)ba[2]; qa.w = (unsigned char)ba[3];
        qb.x = (unsigned char)bb[0]; qb.y = (unsigned char)bb[1];
        qb.z = (unsigned char)bb[2]; qb.w = (unsigned char)bb[3];
        int gq0 = gq_base + ((r0 >> 7) << 4);
        int gq1 = gq_base + ((r1 >> 7) << 4);
        binsq[(size_t)gq0 * 4096 + ((r0 & 127) << 5) + qoff_c] = qa;
        binsq[(size_t)gq1 * 4096 + ((r1 & 127) << 5) + qoff_c] = qb;
    }
#pragma unroll
    for (int m = 1; m < 64; m <<= 1) hotcnt += __shfl_xor(hotcnt, m, 64);
    if (lid == 0 && hotcnt) atomicAdd(&sh[255], (unsigned)hotcnt);
    __syncthreads();

    int wid = t >> 6;
    float h = 0.0f, ex = 0.0f;
    if (t < NBINS) {
        h = (float)sh[t];
        ex = fmaxf(h - CLIP_MAXF, 0.0f);
    }
    float s = ex;
#pragma unroll
    for (int m = 1; m < 64; m <<= 1) s += __shfl_xor(s, m, 64);
    __shared__ float wpart[8];
    if (lid == 0) wpart[wid] = s;
    __syncthreads();
    float excess = wpart[0] + wpart[1] + wpart[2] + wpart[3];

    h = fminf(h, CLIP_MAXF);
    float redist   = floorf(excess * (1.0f / 256.0f));
    float residual = excess - redist * 256.0f;
    h = h + redist + (((float)t < residual) ? 1.0f : 0.0f);

    float c = h;
#pragma unroll
    for (int m = 1; m < 64; m <<= 1) {
        float o = __shfl_up(c, m, 64);
        if (lid >= m) c += o;
    }
    __shared__ float wsum[8];
    if (lid == 63) wsum[wid] = c;
    __syncthreads();
    if (t < NBINS) {
        float off = 0.0f;
        for (int i = 0; i < wid; i++) off += wsum[i];
        c += off;
        float l = fminf(floorf(c * LUT_SCALE), 255.0f);
        l = fmaxf(l, 0.0f);
        lut[((size_t)img * NTPI + tile) * NBINS + t] = l;
    }
}

// vmax == 255 EXACTLY (argmax pixel -> bin 255; every lut[255]=255; v<=255),
// so the final normalize uses pmx = 1 exactly and only vmin must be reduced.

// ---- K34: merged coop kernel: vmin pass + grid sync + final write ----
// 2048 blocks x 256 thr, 4KB LDS, <=64 VGPR -> fully co-resident (8 blk/CU).
// Per-thread bins held in 16 uchar4 REGISTERS across the grid sync, so binsq
// is read exactly once.
__global__ __launch_bounds__(256, 8) void k_vfinal(const uchar4* __restrict__ binsq,
                                                   const float* __restrict__ lut,
                                                   float* __restrict__ red2,
                                                   float4* __restrict__ out) {
    cg::grid_group gg = cg::this_grid();
    __shared__ float4 Lq[NBINS];
    int t = threadIdx.x;
    int qx = blockIdx.x, qy = blockIdx.y, img = blockIdx.z;
    const float* lb = lut + (size_t)img * NTPI * NBINS;
    {
        int ty2 = qy >> 1, tx2 = qx >> 1;
        int yA = (qy & 1) ? ty2 : max(ty2 - 1, 0);
        int yB = (qy & 1) ? min(ty2 + 1, GH - 1) : ty2;
        int xA = (qx & 1) ? tx2 : max(tx2 - 1, 0);
        int xB = (qx & 1) ? min(tx2 + 1, GW - 1) : tx2;
        float4 g;
        g.x = lb[(size_t)(yA * GW + xA) * NBINS + t];
        g.y = lb[(size_t)(yA * GW + xB) * NBINS + t];
        g.z = lb[(size_t)(yB * GW + xA) * NBINS + t];
        g.w = lb[(size_t)(yB * GW + xB) * NBINS + t];
        Lq[t] = g;
    }
    __syncthreads();

    int gq = (img * 16 + qy) * 16 + qx;
    const uchar4* bq = binsq + (size_t)gq * 4096;

    int gy0 = qy << 7, gx0 = qx << 7;
    int rowoff = t >> 5;  // 0..7
    int c4 = t & 31;
    int ix0 = gx0 + (c4 << 2);

    float wxv[4];
#pragma unroll
    for (int j = 0; j < 4; j++) {
        float txf = ((float)(ix0 + j) + 0.5f) * (1.0f / 256.0f) - 0.5f;
        wxv[j] = txf - floorf(txf);
    }

    // load ALL 64 pixels' bins into registers (16-deep MLP), keep across sync
    uchar4 qs[16];
#pragma unroll
    for (int it = 0; it < 16; ++it)
        qs[it] = bq[((it << 3) + rowoff << 5) + c4];

    // phase A: v-min partial
    float vmnl = 3.4e38f;
#pragma unroll
    for (int it = 0; it < 16; ++it) {
        int iy = gy0 + (it << 3) + rowoff;
        float tyf = ((float)iy + 0.5f) * (1.0f / 256.0f) - 0.5f;
        float wy = tyf - floorf(tyf);
        int b[4] = {qs[it].x, qs[it].y, qs[it].z, qs[it].w};
#pragma unroll
        for (int j = 0; j < 4; j++) {
            float4 g = Lq[b[j]];
            float a = g.x + wxv[j] * (g.y - g.x);
            float bbv = g.z + wxv[j] * (g.w - g.z);
            vmnl = fminf(vmnl, a + wy * (bbv - a));
        }
    }
    block_min_all<4>(vmnl, t);
    if (t == 0) red2[gq] = vmnl;
    gg.sync();

    // phase B: reduce partials (redundant per block, L2-hot, deterministic)
    float vmn = 3.4e38f;
#pragma unroll
    for (int k = 0; k < 8; k++) vmn = fminf(vmn, red2[t + k * 256]);
    block_min_all<4>(vmn, t);
    float pmn = vmn * (1.0f / 255.0f);
    float oscale = 1.0f / (1.0f - pmn);   // pmx = 1 exactly
    float s1 = oscale * (1.0f / 255.0f);
    float s2 = -pmn * oscale;

    // renormalize Lq in place (element-wise, then barrier)
    {
        float4 g = Lq[t];
        g.x = g.x * s1 + s2; g.y = g.y * s1 + s2;
        g.z = g.z * s1 + s2; g.w = g.w * s1 + s2;
        Lq[t] = g;
    }
    __syncthreads();

    // phase C: recompute from registers, NT store
#pragma unroll
    for (int it = 0; it < 16; ++it) {
        int r = (it << 3) + rowoff;
        int iy = gy0 + r;
        float tyf = ((float)iy + 0.5f) * (1.0f / 256.0f) - 0.5f;
        float wy = tyf - floorf(tyf);
        int b[4] = {qs[it].x, qs[it].y, qs[it].z, qs[it].w};
        float4 o;
        float* op = &o.x;
#pragma unroll
        for (int j = 0; j < 4; j++) {
            float4 g = Lq[b[j]];
            float a = g.x + wxv[j] * (g.y - g.x);
            float bbv = g.z + wxv[j] * (g.w - g.z);
            op[j] = a + wy * (bbv - a);
        }
        size_t pidx = ((size_t)img * IMH + iy) * IMW + ix0;
        f32x4 ov = {o.x, o.y, o.z, o.w};
        __builtin_nontemporal_store(ov, (f32x4*)&out[pidx >> 2]);
    }
}

// ---- fallback K3/K4 (round-8 exact) ----
__global__ __launch_bounds__(256, 8) void k_vmin(const uchar4* __restrict__ binsq,
                                                 const float* __restrict__ lut,
                                                 float* __restrict__ red2) {
    __shared__ float4 Lq[NBINS];
    int t = threadIdx.x;
    int qx = blockIdx.x, qy = blockIdx.y, img = blockIdx.z;
    const float* lb = lut + (size_t)img * NTPI * NBINS;
    {
        int ty2 = qy >> 1, tx2 = qx >> 1;
        int yA = (qy & 1) ? ty2 : max(ty2 - 1, 0);
        int yB = (qy & 1) ? min(ty2 + 1, GH - 1) : ty2;
        int xA = (qx & 1) ? tx2 : max(tx2 - 1, 0);
        int xB = (qx & 1) ? min(tx2 + 1, GW - 1) : tx2;
        float4 g;
        g.x = lb[(size_t)(yA * GW + xA) * NBINS + t];
        g.y = lb[(size_t)(yA * GW + xB) * NBINS + t];
        g.z = lb[(size_t)(yB * GW + xA) * NBINS + t];
        g.w = lb[(size_t)(yB * GW + xB) * NBINS + t];
        Lq[t] = g;
    }
    __syncthreads();

    int gq = (img * 16 + qy) * 16 + qx;
    const uchar4* bq = binsq + (size_t)gq * 4096;

    float vmnl = 3.4e38f;
    int gy0 = qy << 7;
    int rowoff = t >> 5, c4 = t & 31;
    int ix0 = (qx << 7) + (c4 << 2);

    float wxv[4];
#pragma unroll
    for (int j = 0; j < 4; j++) {
        float txf = ((float)(ix0 + j) + 0.5f) * (1.0f / 256.0f) - 0.5f;
        wxv[j] = txf - floorf(txf);
    }

    for (int it = 0; it < 16; it += 2) {
        int r0 = (it << 3) + rowoff;
        int r1 = ((it + 1) << 3) + rowoff;
        uchar4 qa = bq[(r0 << 5) + c4];
        uchar4 qb = bq[(r1 << 5) + c4];
#pragma unroll
        for (int half = 0; half < 2; ++half) {
            uchar4 q = half ? qb : qa;
            int iy = gy0 + (half ? r1 : r0);
            int b[4] = {q.x, q.y, q.z, q.w};
            float tyf = ((float)iy + 0.5f) * (1.0f / 256.0f) - 0.5f;
            float wy = tyf - floorf(tyf);
#pragma unroll
            for (int j = 0; j < 4; j++) {
                float4 g = Lq[b[j]];
                float a = g.x + wxv[j] * (g.y - g.x);
                float bbv = g.z + wxv[j] * (g.w - g.z);
                vmnl = fminf(vmnl, a + wy * (bbv - a));
            }
        }
    }
    block_min_all<4>(vmnl, t);
    if (t == 0) red2[gq] = vmnl;
}

__global__ __launch_bounds__(256, 8) void k_final(const uchar4* __restrict__ binsq,
                                                  const float* __restrict__ lut,
                                                  const float* __restrict__ red2,
                                                  float4* __restrict__ out) {
    __shared__ float4 Lq[NBINS];
    int t = threadIdx.x;

    float s1, s2;
    {
        float vmn = 3.4e38f;
#pragma unroll
        for (int k = 0; k < 8; k++) vmn = fminf(vmn, red2[t + k * 256]);
        block_min_all<4>(vmn, t);
        float pmn = vmn * (1.0f / 255.0f);
        float oscale = 1.0f / (1.0f - pmn);
        s1 = oscale * (1.0f / 255.0f);
        s2 = -pmn * oscale;
    }

    int qx = blockIdx.x, qy = blockIdx.y, img = blockIdx.z;
    const float* lb = lut + (size_t)img * NTPI * NBINS;
    {
        int ty2 = qy >> 1, tx2 = qx >> 1;
        int yA = (qy & 1) ? ty2 : max(ty2 - 1, 0);
        int yB = (qy & 1) ? min(ty2 + 1, GH - 1) : ty2;
        int xA = (qx & 1) ? tx2 : max(tx2 - 1, 0);
        int xB = (qx & 1) ? min(tx2 + 1, GW - 1) : tx2;
        float4 g;
        g.x = lb[(size_t)(yA * GW + xA) * NBINS + t] * s1 + s2;
        g.y = lb[(size_t)(yA * GW + xB) * NBINS + t] * s1 + s2;
        g.z = lb[(size_t)(yB * GW + xA) * NBINS + t] * s1 + s2;
        g.w = lb[(size_t)(yB * GW + xB) * NBINS + t] * s1 + s2;
        Lq[t] = g;
    }
    __syncthreads();

    int gq = (img * 16 + qy) * 16 + qx;
    const uchar4* bq = binsq + (size_t)gq * 4096;

    int gy0 = qy << 7;
    int rowoff = t >> 5, c4 = t & 31;
    int ix0 = (qx << 7) + (c4 << 2);

    float wxv[4];
#pragma unroll
    for (int j = 0; j < 4; j++) {
        float txf = ((float)(ix0 + j) + 0.5f) * (1.0f / 256.0f) - 0.5f;
        wxv[j] = txf - floorf(txf);
    }

    for (int it = 0; it < 16; it += 2) {
        int r0 = (it << 3) + rowoff;
        int r1 = ((it + 1) << 3) + rowoff;
        uchar4 qa = bq[(r0 << 5) + c4];
        uchar4 qb = bq[(r1 << 5) + c4];
#pragma unroll
        for (int half = 0; half < 2; ++half) {
            uchar4 q = half ? qb : qa;
            int iy = gy0 + (half ? r1 : r0);
            int b[4] = {q.x, q.y, q.z, q.w};
            float tyf = ((float)iy + 0.5f) * (1.0f / 256.0f) - 0.5f;
            float wy = tyf - floorf(tyf);
            float4 o;
            float* op = &o.x;
#pragma unroll
            for (int j = 0; j < 4; j++) {
                float4 g = Lq[b[j]];
                float a = g.x + wxv[j] * (g.y - g.x);
                float bbv = g.z + wxv[j] * (g.w - g.z);
                op[j] = a + wy * (bbv - a);
            }
            size_t pidx = ((size_t)img * IMH + iy) * IMW + ix0;
            f32x4 ov = {o.x, o.y, o.z, o.w};
            __builtin_nontemporal_store(ov, (f32x4*)&out[pidx >> 2]);
        }
    }
}

extern "C" void kernel_launch(void* const* d_in, const int* in_sizes, int n_in,
                              void* d_out, int out_size, void* d_ws, size_t ws_size,
                              hipStream_t stream) {
    const float* x = (const float*)d_in[0];
    float4* out = (float4*)d_out;

    unsigned char* ws = (unsigned char*)d_ws;
    float* lut    = (float*)(ws + 64);                       // 512 KB
    float2* red1  = (float2*)(ws + 64 + 512 * 1024);         // 16 KB (2048 float2)
    float* red2   = (float*)(ws + 64 + 512 * 1024 + 16384);  // 8 KB (2048 float)
    uchar4* binsq = (uchar4*)(ws + 1024 * 1024);             // 33.5 MB quadrant-major

    k_minmax_in<<<dim3(MM_BLOCKS), dim3(256), 0, stream>>>((const float4*)x, red1);
    k_hist<<<dim3(NTPI, NIMG), dim3(512), 0, stream>>>(x, red1, lut, binsq);

    dim3 qgrid(16, 16, NIMG);
    {
        const uchar4* bq = binsq;
        void* args[] = {(void*)&bq, (void*)&lut, (void*)&red2, (void*)&out};
        hipError_t e = hipLaunchCooperativeKernel((const void*)k_vfinal,
                                                  qgrid, dim3(256), args, 0, stream);
        if (e == hipSuccess) return;
        (void)hipGetLastError();  // clear, fall through
    }
    k_vmin<<<qgrid, dim3(256), 0, stream>>>(binsq, lut, red2);
    k_final<<<qgrid, dim3(256), 0, stream>>>(binsq, lut, red2, out);
}

// Round 11
// 104.919 us; speedup vs baseline: 4.1628x; 4.1628x over previous
//
#include <hip/hip_runtime.h>

#define NIMG 8
#define IMH 2048
#define IMW 2048
#define GH 8
#define GW 8
#define NBINS 256
#define NTPI 64                        // tiles per image
#define CLIP_MAXF 256.0f               // clip_limit*pixels//NBINS = 65536//256
#define LUT_SCALE 0.0038909912109375f  // 255/65536, exact in f32
#define LOG_GAIN_F 2.5f

#define MM_BLOCKS 2048                 // k_minmax_in grid (64 KB per block)

typedef float f32x4 __attribute__((ext_vector_type(4)));

// fast bin: wave-uniform inv_den hoists the divide; __log2f = 1 v_log_f32
__device__ __forceinline__ int pix_bin(float v, float mn, float inv_den) {
    float xn = (v - mn) * inv_den;
    float t  = LOG_GAIN_F * __log2f(1.0f + xn);
    float xc = fminf(fmaxf(t, 0.0f), 1.0f);
    int b = (int)(xc * 256.0f);
    return min(max(b, 0), 255);
}

__device__ __forceinline__ void mm4(float4 v, float& mn, float& mx) {
    mn = fminf(mn, fminf(fminf(v.x, v.y), fminf(v.z, v.w)));
    mx = fmaxf(mx, fmaxf(fmaxf(v.x, v.y), fmaxf(v.z, v.w)));
}

template <int NWAVES>
__device__ __forceinline__ void block_minmax_all(float& mn, float& mx, int t) {
#pragma unroll
    for (int m = 32; m >= 1; m >>= 1) {
        mn = fminf(mn, __shfl_xor(mn, m, 64));
        mx = fmaxf(mx, __shfl_xor(mx, m, 64));
    }
    __shared__ float smn[NWAVES], smx[NWAVES];
    int wid = t >> 6, lid = t & 63;
    if (lid == 0) { smn[wid] = mn; smx[wid] = mx; }
    __syncthreads();
    mn = smn[0]; mx = smx[0];
#pragma unroll
    for (int i = 1; i < NWAVES; i++) { mn = fminf(mn, smn[i]); mx = fmaxf(mx, smx[i]); }
}

template <int NWAVES>
__device__ __forceinline__ void block_min_all(float& mn, int t) {
#pragma unroll
    for (int m = 32; m >= 1; m >>= 1) mn = fminf(mn, __shfl_xor(mn, m, 64));
    __shared__ float smn[NWAVES];
    int wid = t >> 6, lid = t & 63;
    if (lid == 0) smn[wid] = mn;
    __syncthreads();
    mn = smn[0];
#pragma unroll
    for (int i = 1; i < NWAVES; i++) mn = fminf(mn, smn[i]);
}

// ---- K1: per-block min/max of input; 8 loads in flight, 8 blocks/CU ----
__global__ __launch_bounds__(256, 8) void k_minmax_in(const float4* __restrict__ x,
                                                      float2* __restrict__ red) {
    int t = threadIdx.x;
    size_t base = (size_t)blockIdx.x * 4096 + t;   // 4096 float4 per block
    float mn = 3.4e38f, mx = -3.4e38f;
#pragma unroll
    for (int half = 0; half < 2; ++half) {
        float4 v[8];
#pragma unroll
        for (int k = 0; k < 8; ++k)
            v[k] = x[base + (size_t)(half * 8 + k) * 256];
#pragma unroll
        for (int k = 0; k < 8; ++k) mm4(v[k], mn, mx);
    }
    block_minmax_all<4>(mn, mx, t);
    if (t == 0) red[blockIdx.x] = make_float2(mn, mx);
}

// ---- K2: min/max reduce + bin + per-tile hist + clip/scan -> LUT ----
// 512 threads per 256x256 tile. bins written QUADRANT-MAJOR: quadrant
// gq = img*256 + qy*16 + qx is a dense 128x128 byte block
// (uchar4 offset = (r&127)*32 + (c4&31)).
__global__ __launch_bounds__(512, 4) void k_hist(const float* __restrict__ x,
                                                 const float2* __restrict__ red1,
                                                 float* __restrict__ lut,
                                                 uchar4* __restrict__ binsq) {
    int t = threadIdx.x;

    float mn, mx;
    {
        float2 p0 = red1[t];
        float2 p1 = red1[t + 512];
        float2 p2 = red1[t + 1024];
        float2 p3 = red1[t + 1536];
        mn = fminf(fminf(p0.x, p1.x), fminf(p2.x, p3.x));
        mx = fmaxf(fmaxf(p0.y, p1.y), fmaxf(p2.y, p3.y));
        block_minmax_all<8>(mn, mx, t);
    }
    float inv_den = 1.0f / (mx - mn);

    __shared__ unsigned sh[NBINS];
    if (t < NBINS) sh[t] = 0u;
    __syncthreads();

    int tile = blockIdx.x;  // 0..63
    int img  = blockIdx.y;  // 0..7
    int ty = tile >> 3, tx = tile & 7;

    size_t base = ((size_t)img * IMH + (size_t)ty * 256) * IMW + (size_t)tx * 256;
    const float* xt = x + base;
    int lid = t & 63;
    int rowoff = t >> 6;   // 0..7
    int c4 = t & 63;       // 0..63 float4 columns
    int qc = c4 >> 5;
    int gq_base = img * 256 + (2 * ty) * 16 + (2 * tx) + qc;  // + 16*qr
    int qoff_c = c4 & 31;

    int hotcnt = 0;
    for (int it = 0; it < 16; ++it) {
        int r0 = (it << 4) + rowoff;
        int r1 = (it << 4) + 8 + rowoff;
        float4 va = *(const float4*)(xt + (size_t)r0 * IMW + (c4 << 2));
        float4 vb = *(const float4*)(xt + (size_t)r1 * IMW + (c4 << 2));

        int ba[4], bb[4];
        ba[0] = pix_bin(va.x, mn, inv_den); ba[1] = pix_bin(va.y, mn, inv_den);
        ba[2] = pix_bin(va.z, mn, inv_den); ba[3] = pix_bin(va.w, mn, inv_den);
        bb[0] = pix_bin(vb.x, mn, inv_den); bb[1] = pix_bin(vb.y, mn, inv_den);
        bb[2] = pix_bin(vb.z, mn, inv_den); bb[3] = pix_bin(vb.w, mn, inv_den);

#pragma unroll
        for (int j = 0; j < 4; j++) {
            hotcnt += (ba[j] == 255);
            if (ba[j] != 255) atomicAdd(&sh[ba[j]], 1u);
            hotcnt += (bb[j] == 255);
            if (bb[j] != 255) atomicAdd(&sh[bb[j]], 1u);
        }
        uchar4 qa, qb;
        qa.x = (unsigned char)ba[0]; qa.y = (unsigned char)ba[1];
        qa.z = (unsigned char)ba[2]; qa.w = (unsigned char)ba[3];
        qb.x = (unsigned char)bb[0]; qb.y = (unsigned char)bb[1];
        qb.z = (unsigned char)bb[2]; qb.w = (unsigned char)bb[3];
        int gq0 = gq_base + ((r0 >> 7) << 4);
        int gq1 = gq_base + ((r1 >> 7) << 4);
        binsq[(size_t)gq0 * 4096 + ((r0 & 127) << 5) + qoff_c] = qa;
        binsq[(size_t)gq1 * 4096 + ((r1 & 127) << 5) + qoff_c] = qb;
    }
#pragma unroll
    for (int m = 1; m < 64; m <<= 1) hotcnt += __shfl_xor(hotcnt, m, 64);
    if (lid == 0 && hotcnt) atomicAdd(&sh[255], (unsigned)hotcnt);
    __syncthreads();

    // ---- LUT build from LDS hist (threads >=256 ride along) ----
    int wid = t >> 6;
    float h = 0.0f, ex = 0.0f;
    if (t < NBINS) {
        h = (float)sh[t];
        ex = fmaxf(h - CLIP_MAXF, 0.0f);
    }
    float s = ex;
#pragma unroll
    for (int m = 1; m < 64; m <<= 1) s += __shfl_xor(s, m, 64);
    __shared__ float wpart[8];
    if (lid == 0) wpart[wid] = s;
    __syncthreads();
    float excess = wpart[0] + wpart[1] + wpart[2] + wpart[3];

    h = fminf(h, CLIP_MAXF);
    float redist   = floorf(excess * (1.0f / 256.0f));
    float residual = excess - redist * 256.0f;
    h = h + redist + (((float)t < residual) ? 1.0f : 0.0f);

    float c = h;
#pragma unroll
    for (int m = 1; m < 64; m <<= 1) {
        float o = __shfl_up(c, m, 64);
        if (lid >= m) c += o;
    }
    __shared__ float wsum[8];
    if (lid == 63) wsum[wid] = c;
    __syncthreads();
    if (t < NBINS) {
        float off = 0.0f;
        for (int i = 0; i < wid; i++) off += wsum[i];
        c += off;
        float l = fminf(floorf(c * LUT_SCALE), 255.0f);
        l = fmaxf(l, 0.0f);
        lut[((size_t)img * NTPI + tile) * NBINS + t] = l;
    }
}

// vmax == 255 EXACTLY (argmax pixel -> bin 255; every lut[255]=255; v<=255),
// so the final normalize uses pmx = 1 exactly and only vmin must be reduced.

// ---- K3: per-quadrant v-min partials (bins read linear, quadrant-major) ----
__global__ __launch_bounds__(256, 8) void k_vmin(const uchar4* __restrict__ binsq,
                                                 const float* __restrict__ lut,
                                                 float* __restrict__ red2) {
    __shared__ float4 Lq[NBINS];
    int t = threadIdx.x;
    int qx = blockIdx.x, qy = blockIdx.y, img = blockIdx.z;
    const float* lb = lut + (size_t)img * NTPI * NBINS;
    {
        int ty2 = qy >> 1, tx2 = qx >> 1;
        int yA = (qy & 1) ? ty2 : max(ty2 - 1, 0);
        int yB = (qy & 1) ? min(ty2 + 1, GH - 1) : ty2;
        int xA = (qx & 1) ? tx2 : max(tx2 - 1, 0);
        int xB = (qx & 1) ? min(tx2 + 1, GW - 1) : tx2;
        float4 g;
        g.x = lb[(size_t)(yA * GW + xA) * NBINS + t];
        g.y = lb[(size_t)(yA * GW + xB) * NBINS + t];
        g.z = lb[(size_t)(yB * GW + xA) * NBINS + t];
        g.w = lb[(size_t)(yB * GW + xB) * NBINS + t];
        Lq[t] = g;
    }
    __syncthreads();

    int gq = (img * 16 + qy) * 16 + qx;
    const uchar4* bq = binsq + (size_t)gq * 4096;

    float vmnl = 3.4e38f;
    int gy0 = qy << 7;
    int rowoff = t >> 5, c4 = t & 31;
    int ix0 = (qx << 7) + (c4 << 2);

    float wxv[4];
#pragma unroll
    for (int j = 0; j < 4; j++) {
        float txf = ((float)(ix0 + j) + 0.5f) * (1.0f / 256.0f) - 0.5f;
        wxv[j] = txf - floorf(txf);
    }

    for (int it = 0; it < 16; it += 2) {
        int r0 = (it << 3) + rowoff;
        int r1 = ((it + 1) << 3) + rowoff;
        uchar4 qa = bq[(r0 << 5) + c4];
        uchar4 qb = bq[(r1 << 5) + c4];
#pragma unroll
        for (int half = 0; half < 2; ++half) {
            uchar4 q = half ? qb : qa;
            int iy = gy0 + (half ? r1 : r0);
            int b[4] = {q.x, q.y, q.z, q.w};
            float tyf = ((float)iy + 0.5f) * (1.0f / 256.0f) - 0.5f;
            float wy = tyf - floorf(tyf);
#pragma unroll
            for (int j = 0; j < 4; j++) {
                float4 g = Lq[b[j]];
                float a = g.x + wxv[j] * (g.y - g.x);
                float bbv = g.z + wxv[j] * (g.w - g.z);
                vmnl = fminf(vmnl, a + wy * (bbv - a));
            }
        }
    }
    block_min_all<4>(vmnl, t);
    if (t == 0) red2[gq] = vmnl;
}

// ---- K4: final pass; normalize folded into Lq; NT stores to out ----
__global__ __launch_bounds__(256, 8) void k_final(const uchar4* __restrict__ binsq,
                                                  const float* __restrict__ lut,
                                                  const float* __restrict__ red2,
                                                  float4* __restrict__ out) {
    __shared__ float4 Lq[NBINS];
    int t = threadIdx.x;

    float s1, s2;
    {
        float vmn = 3.4e38f;
#pragma unroll
        for (int k = 0; k < 8; k++) vmn = fminf(vmn, red2[t + k * 256]);
        block_min_all<4>(vmn, t);
        float pmn = vmn * (1.0f / 255.0f);
        float oscale = 1.0f / (1.0f - pmn);   // pmx = 1 exactly
        s1 = oscale * (1.0f / 255.0f);
        s2 = -pmn * oscale;
    }

    int qx = blockIdx.x, qy = blockIdx.y, img = blockIdx.z;
    const float* lb = lut + (size_t)img * NTPI * NBINS;
    {
        int ty2 = qy >> 1, tx2 = qx >> 1;
        int yA = (qy & 1) ? ty2 : max(ty2 - 1, 0);
        int yB = (qy & 1) ? min(ty2 + 1, GH - 1) : ty2;
        int xA = (qx & 1) ? tx2 : max(tx2 - 1, 0);
        int xB = (qx & 1) ? min(tx2 + 1, GW - 1) : tx2;
        float4 g;
        g.x = lb[(size_t)(yA * GW + xA) * NBINS + t] * s1 + s2;
        g.y = lb[(size_t)(yA * GW + xB) * NBINS + t] * s1 + s2;
        g.z = lb[(size_t)(yB * GW + xA) * NBINS + t] * s1 + s2;
        g.w = lb[(size_t)(yB * GW + xB) * NBINS + t] * s1 + s2;
        Lq[t] = g;
    }
    __syncthreads();

    int gq = (img * 16 + qy) * 16 + qx;
    const uchar4* bq = binsq + (size_t)gq * 4096;

    int gy0 = qy << 7;
    int rowoff = t >> 5, c4 = t & 31;
    int ix0 = (qx << 7) + (c4 << 2);

    float wxv[4];
#pragma unroll
    for (int j = 0; j < 4; j++) {
        float txf = ((float)(ix0 + j) + 0.5f) * (1.0f / 256.0f) - 0.5f;
        wxv[j] = txf - floorf(txf);
    }

    for (int it = 0; it < 16; it += 2) {
        int r0 = (it << 3) + rowoff;
        int r1 = ((it + 1) << 3) + rowoff;
        uchar4 qa = bq[(r0 << 5) + c4];
        uchar4 qb = bq[(r1 << 5) + c4];
#pragma unroll
        for (int half = 0; half < 2; ++half) {
            uchar4 q = half ? qb : qa;
            int iy = gy0 + (half ? r1 : r0);
            int b[4] = {q.x, q.y, q.z, q.w};
            float tyf = ((float)iy + 0.5f) * (1.0f / 256.0f) - 0.5f;
            float wy = tyf - floorf(tyf);
            float4 o;
            float* op = &o.x;
#pragma unroll
            for (int j = 0; j < 4; j++) {
                float4 g = Lq[b[j]];
                float a = g.x + wxv[j] * (g.y - g.x);
                float bbv = g.z + wxv[j] * (g.w - g.z);
                op[j] = a + wy * (bbv - a);
            }
            size_t pidx = ((size_t)img * IMH + iy) * IMW + ix0;
            f32x4 ov = {o.x, o.y, o.z, o.w};
            __builtin_nontemporal_store(ov, (f32x4*)&out[pidx >> 2]);
        }
    }
}

extern "C" void kernel_launch(void* const* d_in, const int* in_sizes, int n_in,
                              void* d_out, int out_size, void* d_ws, size_t ws_size,
                              hipStream_t stream) {
    const float* x = (const float*)d_in[0];
    float4* out = (float4*)d_out;

    unsigned char* ws = (unsigned char*)d_ws;
    float* lut    = (float*)(ws + 64);                       // 512 KB
    float2* red1  = (float2*)(ws + 64 + 512 * 1024);         // 16 KB (2048 float2)
    float* red2   = (float*)(ws + 64 + 512 * 1024 + 16384);  // 8 KB (2048 float)
    uchar4* binsq = (uchar4*)(ws + 1024 * 1024);             // 33.5 MB quadrant-major

    k_minmax_in<<<dim3(MM_BLOCKS), dim3(256), 0, stream>>>((const float4*)x, red1);
    k_hist<<<dim3(NTPI, NIMG), dim3(512), 0, stream>>>(x, red1, lut, binsq);
    dim3 qgrid(16, 16, NIMG);
    k_vmin<<<qgrid, dim3(256), 0, stream>>>(binsq, lut, red2);
    k_final<<<qgrid, dim3(256), 0, stream>>>(binsq, lut, red2, out);
}